// Round 14
// baseline (266.899 us; speedup 1.0000x reference)
//
#include <hip/hip_runtime.h>

typedef __bf16 bf16x8 __attribute__((ext_vector_type(8)));
typedef float  f32x4  __attribute__((ext_vector_type(4)));
typedef float  f32x8  __attribute__((ext_vector_type(8)));
typedef unsigned short ushort;
typedef ushort us8 __attribute__((ext_vector_type(8)));
typedef unsigned int u32x4 __attribute__((ext_vector_type(4)));

constexpr int N_NODES = 50000;
constexpr int N_EDGES = 800000;
constexpr int SLOTS = 64;                     // bucket capacity (mean deg 16, Poisson tail << 64)
constexpr int GE   = N_EDGES / 256;           // 3125 (exact)
constexpr int WBLK = (3 * 9216) / 256;        // 108 (exact)
constexpr int GMF  = (N_NODES + 63) / 64;     // 782 gemm tiles

__device__ inline float h16f(ushort u) {
    union { _Float16 h; ushort u; } cv; cv.u = u; return (float)cv.h;
}
__device__ inline ushort f16b(float f) {
    union { _Float16 h; ushort u; } cv; cv.h = (_Float16)f; return cv.u;
}
__device__ inline ushort bf16b(float f) {
    union { __bf16 b; ushort u; } cv; cv.b = (__bf16)f; return cv.u;
}
__device__ inline f32x8 bf8_to_f32(us8 u) {
    f32x8 r;
#pragma unroll
    for (int i = 0; i < 8; ++i) r[i] = __uint_as_float(((unsigned int)u[i]) << 16);
    return r;
}
// nontemporal 16 B gather (bypass L1 — random reads have ~0 L1 hit rate)
__device__ inline us8 ld_nt(const ushort* p) {
    u32x4 v = __builtin_nontemporal_load((const u32x4*)p);
    union { u32x4 q; us8 u; } cv; cv.q = v; return cv.u;
}

// ---------------- count (+rank) + W-prep ----------------
__global__ __launch_bounds__(256) void k_count(const int* __restrict__ dst,
                                               int* __restrict__ cnt,
                                               ushort* __restrict__ rank,
                                               const float* __restrict__ W0,
                                               const float* __restrict__ W1,
                                               const float* __restrict__ W2,
                                               ushort* __restrict__ Wt) {
    const int b = blockIdx.x;
    if (b < GE) {
        int e = b * 256 + threadIdx.x;
        rank[e] = (ushort)atomicAdd(&cnt[dst[e]], 1);
    } else {
        int i = (b - GE) * 256 + threadIdx.x;   // exact
        int m = i / 9216, li = i - m * 9216;
        const float* W = (m == 0) ? W0 : (m == 1) ? W1 : W2;
        int k = li / 96, c = li - k * 96;
        Wt[m * 9216 + c * 96 + k] = bf16b(W[li]);
    }
}

// ---------------- MFMA part: sX[64x96] @ sW[96x96] ([c][k]) -> Y rows ----------------
__device__ __forceinline__ void mfma_store(const ushort* sX, const ushort* sW,
                                           ushort* __restrict__ Y, int rowbase) {
    const int tid = threadIdx.x;
    const int wv = tid >> 6, lane = tid & 63, quad = lane >> 4, l16 = lane & 15;
    f32x4 acc[6];
#pragma unroll
    for (int t = 0; t < 6; ++t) acc[t] = (f32x4){0.f, 0.f, 0.f, 0.f};

    const ushort* ax = sX + (wv * 16 + l16) * 96 + quad * 8;
#pragma unroll
    for (int s = 0; s < 3; ++s) {
        bf16x8 a = *(const bf16x8*)(ax + s * 32);
#pragma unroll
        for (int t = 0; t < 6; ++t) {
            bf16x8 b = *(const bf16x8*)(sW + (t * 16 + l16) * 96 + s * 32 + quad * 8);
            acc[t] = __builtin_amdgcn_mfma_f32_16x16x32_bf16(a, b, acc[t], 0, 0, 0);
        }
    }
    // C/D layout: col = lane&15, row = quad*4 + reg
    const int r0 = rowbase + wv * 16 + quad * 4;
#pragma unroll
    for (int t = 0; t < 6; ++t) {
#pragma unroll
        for (int g = 0; g < 4; ++g) {
            int r = r0 + g;
            if (r < N_NODES) Y[(size_t)r * 96 + t * 16 + l16] = bf16b(acc[t][g]);
        }
    }
}

// ---------------- fused: fill (blocks [0,GE)) || gemm layer 1 (blocks [GE,GE+GMF)) ----------------
__global__ __launch_bounds__(256) void k_fill_gemm1(const int* __restrict__ src,
                                                    const int* __restrict__ dst,
                                                    const int* __restrict__ cnt,
                                                    const ushort* __restrict__ rank,
                                                    unsigned int* __restrict__ csr,
                                                    const float* __restrict__ x,
                                                    const ushort* __restrict__ Wt,
                                                    ushort* __restrict__ H) {
    __shared__ ushort sS[64 * 96 + 96 * 96];   // 30 KB (only gemm blocks use it)
    const int b = blockIdx.x;
    const int tid = threadIdx.x;
    if (b < GE) {
        int e = b * 256 + tid;   // GE*256 == N_EDGES, exact
        int s = src[e], d = dst[e];
        float hs = rsqrtf((float)(cnt[s] + 1));
        unsigned int entry = (unsigned int)(ushort)s | ((unsigned int)f16b(hs) << 16);
        csr[(size_t)d * SLOTS + rank[e]] = entry;
    } else {
        ushort* sX = sS;
        ushort* sW = sS + 64 * 96;
        const int rowbase = (b - GE) * 64;
        for (int i = tid; i < 9216 / 8; i += 256)
            ((uint4*)sW)[i] = ((const uint4*)Wt)[i];
        for (int i = tid; i < 64 * 24; i += 256) {
            int r = i / 24, c4 = i % 24;
            int gr = rowbase + r;
            float4 v = make_float4(0.f, 0.f, 0.f, 0.f);
            if (gr < N_NODES) v = ((const float4*)(x + (size_t)gr * 96))[c4];
            ushort* p = sX + r * 96 + c4 * 4;
            p[0] = bf16b(v.x); p[1] = bf16b(v.y); p[2] = bf16b(v.z); p[3] = bf16b(v.w);
        }
        __syncthreads();
        mfma_store(sX, sW, H, rowbase);
    }
}

// ---------------- standalone gemm (layers 2,3) ----------------
__global__ __launch_bounds__(256) void k_gemm_b(const ushort* __restrict__ X,
                                                const ushort* __restrict__ Wt,
                                                ushort* __restrict__ Y) {
    __shared__ ushort sS[64 * 96 + 96 * 96];
    ushort* sX = sS;
    ushort* sW = sS + 64 * 96;
    const int tid = threadIdx.x;
    const int rowbase = blockIdx.x * 64;
    for (int i = tid; i < 9216 / 8; i += 256)
        ((uint4*)sW)[i] = ((const uint4*)Wt)[i];
    for (int i = tid; i < 64 * 12; i += 256) {
        int r = i / 12, c8 = i % 12;
        int gr = rowbase + r;
        uint4 v = make_uint4(0, 0, 0, 0);
        if (gr < N_NODES) v = ((const uint4*)(X + (size_t)gr * 96))[c8];
        ((uint4*)(sX + r * 96))[c8] = v;
    }
    __syncthreads();
    mfma_store(sX, sW, Y, rowbase);
}

// ---------------- fused aggregate (bucket CSR, packed entries, unroll 8) ----------------
// 192 threads = 16 nodes x 12 chunks of 8 feats. N_NODES % 16 == 0 -> exact grid.
// MODE 0: out = bf16 H'   MODE 1: fused final fc -> out4
template<int MODE>
__global__ __launch_bounds__(192) void k_agg(const ushort* __restrict__ A,
                                             const int* __restrict__ cnt,
                                             const unsigned int* __restrict__ csr,
                                             const float* __restrict__ bias,
                                             ushort* __restrict__ Hout,
                                             float* __restrict__ out4,
                                             const float* __restrict__ Wfc,
                                             const float* __restrict__ bfc) {
    __shared__ float sWfc[384];
    __shared__ float red[16][12][4];
    const int tid = threadIdx.x;
    if (MODE == 1) {
        for (int i = tid; i < 384; i += 192) sWfc[i] = Wfc[i];
        __syncthreads();
    }
    const int g = tid / 12, c = tid % 12;
    const int n = blockIdx.x * 16 + g;

    const int deg = cnt[n];
    const float dn = rsqrtf((float)(deg + 1));
    us8 a0 = *(const us8*)(A + (size_t)n * 96 + c * 8);
    f32x8 acc = bf8_to_f32(a0) * (dn * dn);

    const unsigned int* row = csr + (size_t)n * SLOTS;
    int j = 0;
    // 8-edge unroll: 8 independent nontemporal gathers in flight per thread
    for (; j + 8 <= deg; j += 8) {
        const uint4 q0 = *(const uint4*)(row + j);       // broadcast across 12 chunk-threads
        const uint4 q1 = *(const uint4*)(row + j + 4);
        const us8 u0 = ld_nt(A + (size_t)(q0.x & 0xFFFFu) * 96 + c * 8);
        const us8 u1 = ld_nt(A + (size_t)(q0.y & 0xFFFFu) * 96 + c * 8);
        const us8 u2 = ld_nt(A + (size_t)(q0.z & 0xFFFFu) * 96 + c * 8);
        const us8 u3 = ld_nt(A + (size_t)(q0.w & 0xFFFFu) * 96 + c * 8);
        const us8 u4 = ld_nt(A + (size_t)(q1.x & 0xFFFFu) * 96 + c * 8);
        const us8 u5 = ld_nt(A + (size_t)(q1.y & 0xFFFFu) * 96 + c * 8);
        const us8 u6 = ld_nt(A + (size_t)(q1.z & 0xFFFFu) * 96 + c * 8);
        const us8 u7 = ld_nt(A + (size_t)(q1.w & 0xFFFFu) * 96 + c * 8);
        acc += bf8_to_f32(u0) * (h16f((ushort)(q0.x >> 16)) * dn);
        acc += bf8_to_f32(u1) * (h16f((ushort)(q0.y >> 16)) * dn);
        acc += bf8_to_f32(u2) * (h16f((ushort)(q0.z >> 16)) * dn);
        acc += bf8_to_f32(u3) * (h16f((ushort)(q0.w >> 16)) * dn);
        acc += bf8_to_f32(u4) * (h16f((ushort)(q1.x >> 16)) * dn);
        acc += bf8_to_f32(u5) * (h16f((ushort)(q1.y >> 16)) * dn);
        acc += bf8_to_f32(u6) * (h16f((ushort)(q1.z >> 16)) * dn);
        acc += bf8_to_f32(u7) * (h16f((ushort)(q1.w >> 16)) * dn);
    }
    for (; j + 4 <= deg; j += 4) {
        const uint4 q = *(const uint4*)(row + j);
        const us8 u0 = ld_nt(A + (size_t)(q.x & 0xFFFFu) * 96 + c * 8);
        const us8 u1 = ld_nt(A + (size_t)(q.y & 0xFFFFu) * 96 + c * 8);
        const us8 u2 = ld_nt(A + (size_t)(q.z & 0xFFFFu) * 96 + c * 8);
        const us8 u3 = ld_nt(A + (size_t)(q.w & 0xFFFFu) * 96 + c * 8);
        acc += bf8_to_f32(u0) * (h16f((ushort)(q.x >> 16)) * dn);
        acc += bf8_to_f32(u1) * (h16f((ushort)(q.y >> 16)) * dn);
        acc += bf8_to_f32(u2) * (h16f((ushort)(q.z >> 16)) * dn);
        acc += bf8_to_f32(u3) * (h16f((ushort)(q.w >> 16)) * dn);
    }
    for (; j < deg; ++j) {
        const unsigned int e = row[j];
        const float w = h16f((ushort)(e >> 16)) * dn;
        const us8 u = ld_nt(A + (size_t)(e & 0xFFFFu) * 96 + c * 8);
        acc += bf8_to_f32(u) * w;
    }
#pragma unroll
    for (int f = 0; f < 8; ++f) acc[f] = fmaxf(acc[f] + bias[c * 8 + f], 0.0f);

    if (MODE == 0) {
        us8 o;
#pragma unroll
        for (int f = 0; f < 8; ++f) o[f] = bf16b(acc[f]);
        *(us8*)(Hout + (size_t)n * 96 + c * 8) = o;
    } else {
        float p0 = 0.f, p1 = 0.f, p2 = 0.f, p3 = 0.f;
#pragma unroll
        for (int f = 0; f < 8; ++f) {
            const float* wr = sWfc + (c * 8 + f) * 4;
            p0 += acc[f] * wr[0];
            p1 += acc[f] * wr[1];
            p2 += acc[f] * wr[2];
            p3 += acc[f] * wr[3];
        }
        red[g][c][0] = p0; red[g][c][1] = p1; red[g][c][2] = p2; red[g][c][3] = p3;
        __syncthreads();
        if (tid < 64) {
            const int gg = tid >> 2, jj = tid & 3;
            float s = bfc[jj];
#pragma unroll
            for (int cc = 0; cc < 12; ++cc) s += red[gg][cc][jj];
            out4[(size_t)(blockIdx.x * 16 + gg) * 4 + jj] = s;
        }
    }
}

// ---------------- launch ----------------
extern "C" void kernel_launch(void* const* d_in, const int* in_sizes, int n_in,
                              void* d_out, int out_size, void* d_ws, size_t ws_size,
                              hipStream_t stream) {
    const float* x   = (const float*)d_in[0];
    const int*   ei  = (const int*)d_in[1];
    const int*   src = ei;
    const int*   dst = ei + N_EDGES;
    const float* W0  = (const float*)d_in[2];
    const float* b0  = (const float*)d_in[3];
    const float* W1  = (const float*)d_in[4];
    const float* b1  = (const float*)d_in[5];
    const float* W2  = (const float*)d_in[6];
    const float* b2  = (const float*)d_in[7];
    const float* Wfc = (const float*)d_in[8];
    const float* bfc = (const float*)d_in[9];
    float* out = (float*)d_out;

    // workspace layout (16 B-aligned blocks)
    char* w = (char*)d_ws;
    unsigned int* csr = (unsigned int*)w;  w += ((size_t)N_NODES * SLOTS * 4 + 15) & ~15ULL;
    int*    cnt  = (int*)w;                w += ((size_t)N_NODES * 4 + 15) & ~15ULL;
    ushort* rank = (ushort*)w;             w += ((size_t)N_EDGES * 2 + 15) & ~15ULL;
    ushort* Wt   = (ushort*)w;             w += ((size_t)3 * 9216 * 2 + 15) & ~15ULL;
    ushort* H    = (ushort*)w;             w += ((size_t)N_NODES * 96 * 2 + 15) & ~15ULL;
    ushort* G    = (ushort*)w;             // N_NODES * 96 bf16

    const int gAgg = N_NODES / 16;          // 3125, exact

    (void)hipMemsetAsync(cnt, 0, (size_t)N_NODES * 4, stream);
    hipLaunchKernelGGL(k_count, dim3(GE + WBLK), dim3(256), 0, stream,
                       dst, cnt, rank, W0, W1, W2, Wt);
    // fill || gemm layer 1 (independent): one dispatch
    hipLaunchKernelGGL(k_fill_gemm1, dim3(GE + GMF), dim3(256), 0, stream,
                       src, dst, cnt, rank, csr, x, Wt, H);
    // Layer 1 agg
    hipLaunchKernelGGL((k_agg<0>), dim3(gAgg), dim3(192), 0, stream,
                       H, cnt, csr, b0, G, (float*)nullptr,
                       (const float*)nullptr, (const float*)nullptr);
    // Layer 2
    hipLaunchKernelGGL(k_gemm_b, dim3(GMF), dim3(256), 0, stream, G, Wt + 9216, H);
    hipLaunchKernelGGL((k_agg<0>), dim3(gAgg), dim3(192), 0, stream,
                       H, cnt, csr, b1, G, (float*)nullptr,
                       (const float*)nullptr, (const float*)nullptr);
    // Layer 3 + fused fc
    hipLaunchKernelGGL(k_gemm_b, dim3(GMF), dim3(256), 0, stream, G, Wt + 2 * 9216, H);
    hipLaunchKernelGGL((k_agg<1>), dim3(gAgg), dim3(192), 0, stream,
                       H, cnt, csr, b2, (ushort*)nullptr, out, Wfc, bfc);
}

// Round 15
// 237.593 us; speedup vs baseline: 1.1233x; 1.1233x over previous
//
#include <hip/hip_runtime.h>

typedef __bf16 bf16x8 __attribute__((ext_vector_type(8)));
typedef float  f32x4  __attribute__((ext_vector_type(4)));
typedef float  f32x8  __attribute__((ext_vector_type(8)));
typedef unsigned short ushort;
typedef ushort us8 __attribute__((ext_vector_type(8)));

constexpr int N_NODES = 50000;
constexpr int N_EDGES = 800000;
constexpr int SLOTS = 64;                     // bucket capacity (mean deg 16, Poisson tail << 64)
constexpr int GE   = N_EDGES / 256;           // 3125 (exact)
constexpr int WBLK = (3 * 9216) / 256;        // 108 (exact)
constexpr int GMF  = (N_NODES + 63) / 64;     // 782 gemm tiles

__device__ inline float h16f(ushort u) {
    union { _Float16 h; ushort u; } cv; cv.u = u; return (float)cv.h;
}
__device__ inline ushort f16b(float f) {
    union { _Float16 h; ushort u; } cv; cv.h = (_Float16)f; return cv.u;
}
__device__ inline ushort bf16b(float f) {
    union { __bf16 b; ushort u; } cv; cv.b = (__bf16)f; return cv.u;
}
__device__ inline f32x8 bf8_to_f32(us8 u) {
    f32x8 r;
#pragma unroll
    for (int i = 0; i < 8; ++i) r[i] = __uint_as_float(((unsigned int)u[i]) << 16);
    return r;
}

// ---------------- count (+rank) + W-prep ----------------
__global__ __launch_bounds__(256) void k_count(const int* __restrict__ dst,
                                               int* __restrict__ cnt,
                                               ushort* __restrict__ rank,
                                               const float* __restrict__ W0,
                                               const float* __restrict__ W1,
                                               const float* __restrict__ W2,
                                               ushort* __restrict__ Wt) {
    const int b = blockIdx.x;
    if (b < GE) {
        int e = b * 256 + threadIdx.x;
        rank[e] = (ushort)atomicAdd(&cnt[dst[e]], 1);
    } else {
        int i = (b - GE) * 256 + threadIdx.x;   // exact
        int m = i / 9216, li = i - m * 9216;
        const float* W = (m == 0) ? W0 : (m == 1) ? W1 : W2;
        int k = li / 96, c = li - k * 96;
        Wt[m * 9216 + c * 96 + k] = bf16b(W[li]);
    }
}

// ---------------- MFMA part: sX[64x96] @ sW[96x96] ([c][k]) -> Y rows ----------------
__device__ __forceinline__ void mfma_store(const ushort* sX, const ushort* sW,
                                           ushort* __restrict__ Y, int rowbase) {
    const int tid = threadIdx.x;
    const int wv = tid >> 6, lane = tid & 63, quad = lane >> 4, l16 = lane & 15;
    f32x4 acc[6];
#pragma unroll
    for (int t = 0; t < 6; ++t) acc[t] = (f32x4){0.f, 0.f, 0.f, 0.f};

    const ushort* ax = sX + (wv * 16 + l16) * 96 + quad * 8;
#pragma unroll
    for (int s = 0; s < 3; ++s) {
        bf16x8 a = *(const bf16x8*)(ax + s * 32);
#pragma unroll
        for (int t = 0; t < 6; ++t) {
            bf16x8 b = *(const bf16x8*)(sW + (t * 16 + l16) * 96 + s * 32 + quad * 8);
            acc[t] = __builtin_amdgcn_mfma_f32_16x16x32_bf16(a, b, acc[t], 0, 0, 0);
        }
    }
    // C/D layout: col = lane&15, row = quad*4 + reg
    const int r0 = rowbase + wv * 16 + quad * 4;
#pragma unroll
    for (int t = 0; t < 6; ++t) {
#pragma unroll
        for (int g = 0; g < 4; ++g) {
            int r = r0 + g;
            if (r < N_NODES) Y[(size_t)r * 96 + t * 16 + l16] = bf16b(acc[t][g]);
        }
    }
}

// ---------------- fused: fill (blocks [0,GE)) || gemm layer 1 (blocks [GE,GE+GMF)) ----------------
__global__ __launch_bounds__(256) void k_fill_gemm1(const int* __restrict__ src,
                                                    const int* __restrict__ dst,
                                                    const int* __restrict__ cnt,
                                                    const ushort* __restrict__ rank,
                                                    unsigned int* __restrict__ csr,
                                                    const float* __restrict__ x,
                                                    const ushort* __restrict__ Wt,
                                                    ushort* __restrict__ H) {
    __shared__ ushort sS[64 * 96 + 96 * 96];   // 30 KB (only gemm blocks use it)
    const int b = blockIdx.x;
    const int tid = threadIdx.x;
    if (b < GE) {
        int e = b * 256 + tid;   // GE*256 == N_EDGES, exact
        int s = src[e], d = dst[e];
        float hs = rsqrtf((float)(cnt[s] + 1));
        unsigned int entry = (unsigned int)(ushort)s | ((unsigned int)f16b(hs) << 16);
        csr[(size_t)d * SLOTS + rank[e]] = entry;
    } else {
        ushort* sX = sS;
        ushort* sW = sS + 64 * 96;
        const int rowbase = (b - GE) * 64;
        for (int i = tid; i < 9216 / 8; i += 256)
            ((uint4*)sW)[i] = ((const uint4*)Wt)[i];
        for (int i = tid; i < 64 * 24; i += 256) {
            int r = i / 24, c4 = i % 24;
            int gr = rowbase + r;
            float4 v = make_float4(0.f, 0.f, 0.f, 0.f);
            if (gr < N_NODES) v = ((const float4*)(x + (size_t)gr * 96))[c4];
            ushort* p = sX + r * 96 + c4 * 4;
            p[0] = bf16b(v.x); p[1] = bf16b(v.y); p[2] = bf16b(v.z); p[3] = bf16b(v.w);
        }
        __syncthreads();
        mfma_store(sX, sW, H, rowbase);
    }
}

// ---------------- standalone gemm (layers 2,3) ----------------
__global__ __launch_bounds__(256) void k_gemm_b(const ushort* __restrict__ X,
                                                const ushort* __restrict__ Wt,
                                                ushort* __restrict__ Y) {
    __shared__ ushort sS[64 * 96 + 96 * 96];
    ushort* sX = sS;
    ushort* sW = sS + 64 * 96;
    const int tid = threadIdx.x;
    const int rowbase = blockIdx.x * 64;
    for (int i = tid; i < 9216 / 8; i += 256)
        ((uint4*)sW)[i] = ((const uint4*)Wt)[i];
    for (int i = tid; i < 64 * 12; i += 256) {
        int r = i / 12, c8 = i % 12;
        int gr = rowbase + r;
        uint4 v = make_uint4(0, 0, 0, 0);
        if (gr < N_NODES) v = ((const uint4*)(X + (size_t)gr * 96))[c8];
        ((uint4*)(sX + r * 96))[c8] = v;
    }
    __syncthreads();
    mfma_store(sX, sW, Y, rowbase);
}

// ---------------- fused aggregate (bucket CSR, packed entries, unroll 8, cached loads) ----------------
// 192 threads = 16 nodes x 12 chunks of 8 feats. N_NODES % 16 == 0 -> exact grid.
// MODE 0: out = bf16 H'   MODE 1: fused final fc -> out4
template<int MODE>
__global__ __launch_bounds__(192) void k_agg(const ushort* __restrict__ A,
                                             const int* __restrict__ cnt,
                                             const unsigned int* __restrict__ csr,
                                             const float* __restrict__ bias,
                                             ushort* __restrict__ Hout,
                                             float* __restrict__ out4,
                                             const float* __restrict__ Wfc,
                                             const float* __restrict__ bfc) {
    __shared__ float sWfc[384];
    __shared__ float red[16][12][4];
    const int tid = threadIdx.x;
    if (MODE == 1) {
        for (int i = tid; i < 384; i += 192) sWfc[i] = Wfc[i];
        __syncthreads();
    }
    const int g = tid / 12, c = tid % 12;
    const int n = blockIdx.x * 16 + g;

    const int deg = cnt[n];
    const float dn = rsqrtf((float)(deg + 1));
    us8 a0 = *(const us8*)(A + (size_t)n * 96 + c * 8);
    f32x8 acc = bf8_to_f32(a0) * (dn * dn);

    const unsigned int* row = csr + (size_t)n * SLOTS;
    int j = 0;
    // 8-edge unroll: 8 independent gathers in flight per thread (plain cached loads)
    for (; j + 8 <= deg; j += 8) {
        const uint4 q0 = *(const uint4*)(row + j);       // broadcast across 12 chunk-threads
        const uint4 q1 = *(const uint4*)(row + j + 4);
        const us8 u0 = *(const us8*)(A + (size_t)(q0.x & 0xFFFFu) * 96 + c * 8);
        const us8 u1 = *(const us8*)(A + (size_t)(q0.y & 0xFFFFu) * 96 + c * 8);
        const us8 u2 = *(const us8*)(A + (size_t)(q0.z & 0xFFFFu) * 96 + c * 8);
        const us8 u3 = *(const us8*)(A + (size_t)(q0.w & 0xFFFFu) * 96 + c * 8);
        const us8 u4 = *(const us8*)(A + (size_t)(q1.x & 0xFFFFu) * 96 + c * 8);
        const us8 u5 = *(const us8*)(A + (size_t)(q1.y & 0xFFFFu) * 96 + c * 8);
        const us8 u6 = *(const us8*)(A + (size_t)(q1.z & 0xFFFFu) * 96 + c * 8);
        const us8 u7 = *(const us8*)(A + (size_t)(q1.w & 0xFFFFu) * 96 + c * 8);
        acc += bf8_to_f32(u0) * (h16f((ushort)(q0.x >> 16)) * dn);
        acc += bf8_to_f32(u1) * (h16f((ushort)(q0.y >> 16)) * dn);
        acc += bf8_to_f32(u2) * (h16f((ushort)(q0.z >> 16)) * dn);
        acc += bf8_to_f32(u3) * (h16f((ushort)(q0.w >> 16)) * dn);
        acc += bf8_to_f32(u4) * (h16f((ushort)(q1.x >> 16)) * dn);
        acc += bf8_to_f32(u5) * (h16f((ushort)(q1.y >> 16)) * dn);
        acc += bf8_to_f32(u6) * (h16f((ushort)(q1.z >> 16)) * dn);
        acc += bf8_to_f32(u7) * (h16f((ushort)(q1.w >> 16)) * dn);
    }
    for (; j + 4 <= deg; j += 4) {
        const uint4 q = *(const uint4*)(row + j);
        const us8 u0 = *(const us8*)(A + (size_t)(q.x & 0xFFFFu) * 96 + c * 8);
        const us8 u1 = *(const us8*)(A + (size_t)(q.y & 0xFFFFu) * 96 + c * 8);
        const us8 u2 = *(const us8*)(A + (size_t)(q.z & 0xFFFFu) * 96 + c * 8);
        const us8 u3 = *(const us8*)(A + (size_t)(q.w & 0xFFFFu) * 96 + c * 8);
        acc += bf8_to_f32(u0) * (h16f((ushort)(q.x >> 16)) * dn);
        acc += bf8_to_f32(u1) * (h16f((ushort)(q.y >> 16)) * dn);
        acc += bf8_to_f32(u2) * (h16f((ushort)(q.z >> 16)) * dn);
        acc += bf8_to_f32(u3) * (h16f((ushort)(q.w >> 16)) * dn);
    }
    for (; j < deg; ++j) {
        const unsigned int e = row[j];
        const float w = h16f((ushort)(e >> 16)) * dn;
        const us8 u = *(const us8*)(A + (size_t)(e & 0xFFFFu) * 96 + c * 8);
        acc += bf8_to_f32(u) * w;
    }
#pragma unroll
    for (int f = 0; f < 8; ++f) acc[f] = fmaxf(acc[f] + bias[c * 8 + f], 0.0f);

    if (MODE == 0) {
        us8 o;
#pragma unroll
        for (int f = 0; f < 8; ++f) o[f] = bf16b(acc[f]);
        *(us8*)(Hout + (size_t)n * 96 + c * 8) = o;
    } else {
        float p0 = 0.f, p1 = 0.f, p2 = 0.f, p3 = 0.f;
#pragma unroll
        for (int f = 0; f < 8; ++f) {
            const float* wr = sWfc + (c * 8 + f) * 4;
            p0 += acc[f] * wr[0];
            p1 += acc[f] * wr[1];
            p2 += acc[f] * wr[2];
            p3 += acc[f] * wr[3];
        }
        red[g][c][0] = p0; red[g][c][1] = p1; red[g][c][2] = p2; red[g][c][3] = p3;
        __syncthreads();
        if (tid < 64) {
            const int gg = tid >> 2, jj = tid & 3;
            float s = bfc[jj];
#pragma unroll
            for (int cc = 0; cc < 12; ++cc) s += red[gg][cc][jj];
            out4[(size_t)(blockIdx.x * 16 + gg) * 4 + jj] = s;
        }
    }
}

// ---------------- launch ----------------
extern "C" void kernel_launch(void* const* d_in, const int* in_sizes, int n_in,
                              void* d_out, int out_size, void* d_ws, size_t ws_size,
                              hipStream_t stream) {
    const float* x   = (const float*)d_in[0];
    const int*   ei  = (const int*)d_in[1];
    const int*   src = ei;
    const int*   dst = ei + N_EDGES;
    const float* W0  = (const float*)d_in[2];
    const float* b0  = (const float*)d_in[3];
    const float* W1  = (const float*)d_in[4];
    const float* b1  = (const float*)d_in[5];
    const float* W2  = (const float*)d_in[6];
    const float* b2  = (const float*)d_in[7];
    const float* Wfc = (const float*)d_in[8];
    const float* bfc = (const float*)d_in[9];
    float* out = (float*)d_out;

    // workspace layout (16 B-aligned blocks)
    char* w = (char*)d_ws;
    unsigned int* csr = (unsigned int*)w;  w += ((size_t)N_NODES * SLOTS * 4 + 15) & ~15ULL;
    int*    cnt  = (int*)w;                w += ((size_t)N_NODES * 4 + 15) & ~15ULL;
    ushort* rank = (ushort*)w;             w += ((size_t)N_EDGES * 2 + 15) & ~15ULL;
    ushort* Wt   = (ushort*)w;             w += ((size_t)3 * 9216 * 2 + 15) & ~15ULL;
    ushort* H    = (ushort*)w;             w += ((size_t)N_NODES * 96 * 2 + 15) & ~15ULL;
    ushort* G    = (ushort*)w;             // N_NODES * 96 bf16

    const int gAgg = N_NODES / 16;          // 3125, exact

    (void)hipMemsetAsync(cnt, 0, (size_t)N_NODES * 4, stream);
    hipLaunchKernelGGL(k_count, dim3(GE + WBLK), dim3(256), 0, stream,
                       dst, cnt, rank, W0, W1, W2, Wt);
    // fill || gemm layer 1 (independent): one dispatch
    hipLaunchKernelGGL(k_fill_gemm1, dim3(GE + GMF), dim3(256), 0, stream,
                       src, dst, cnt, rank, csr, x, Wt, H);
    // Layer 1 agg
    hipLaunchKernelGGL((k_agg<0>), dim3(gAgg), dim3(192), 0, stream,
                       H, cnt, csr, b0, G, (float*)nullptr,
                       (const float*)nullptr, (const float*)nullptr);
    // Layer 2
    hipLaunchKernelGGL(k_gemm_b, dim3(GMF), dim3(256), 0, stream, G, Wt + 9216, H);
    hipLaunchKernelGGL((k_agg<0>), dim3(gAgg), dim3(192), 0, stream,
                       H, cnt, csr, b1, G, (float*)nullptr,
                       (const float*)nullptr, (const float*)nullptr);
    // Layer 3 + fused fc
    hipLaunchKernelGGL(k_gemm_b, dim3(GMF), dim3(256), 0, stream, G, Wt + 2 * 9216, H);
    hipLaunchKernelGGL((k_agg<1>), dim3(gAgg), dim3(192), 0, stream,
                       H, cnt, csr, b2, (ushort*)nullptr, out, Wfc, bfc);
}